// Round 3
// baseline (166.126 us; speedup 1.0000x reference)
//
#include <hip/hip_runtime.h>
#include <stdint.h>

typedef unsigned short u16;
typedef __attribute__((ext_vector_type(8))) short short8;   // 8 x bf16 (4 VGPRs)
typedef __attribute__((ext_vector_type(4))) short short4v;  // 4 x bf16
typedef __attribute__((ext_vector_type(4))) float f32x4;

#define AS1 __attribute__((address_space(1)))
#define AS3 __attribute__((address_space(3)))

__device__ __forceinline__ u16 f2bf(float f) {
  uint32_t x = __builtin_bit_cast(uint32_t, f);
  uint32_t r = (x + 0x7fffu + ((x >> 16) & 1u)) >> 16;   // RNE
  return (u16)r;
}
__device__ __forceinline__ float bf2f(u16 u) {
  return __builtin_bit_cast(float, (uint32_t)u << 16);
}

// ---------------- pack: fp32 -> bf16 conversions + weight concat ----------------
__device__ __forceinline__ void conv8(const float* __restrict__ s, u16* __restrict__ d, float sc) {
  float4 a = *(const float4*)s;
  float4 b = *(const float4*)(s + 4);
  union { u16 u[8]; uint4 v; } pk;
  pk.u[0] = f2bf(a.x * sc); pk.u[1] = f2bf(a.y * sc); pk.u[2] = f2bf(a.z * sc); pk.u[3] = f2bf(a.w * sc);
  pk.u[4] = f2bf(b.x * sc); pk.u[5] = f2bf(b.y * sc); pk.u[6] = f2bf(b.z * sc); pk.u[7] = f2bf(b.w * sc);
  *(uint4*)d = pk.v;
}
__device__ __forceinline__ void copy8f(const float* __restrict__ s, float* __restrict__ d, float sc) {
  float4 a = *(const float4*)s;
  float4 b = *(const float4*)(s + 4);
  a.x *= sc; a.y *= sc; a.z *= sc; a.w *= sc;
  b.x *= sc; b.y *= sc; b.z *= sc; b.w *= sc;
  *(float4*)d = a; *(float4*)(d + 4) = b;
}

__global__ void pack_kernel(const float* __restrict__ X,
                            const float* __restrict__ Wq, const float* __restrict__ bq,
                            const float* __restrict__ Wk, const float* __restrict__ bk,
                            const float* __restrict__ Wv, const float* __restrict__ bv,
                            const float* __restrict__ Wo,
                            u16* __restrict__ Xbf, u16* __restrict__ Wcat,
                            u16* __restrict__ Wobf, float* __restrict__ bcat) {
  int t = blockIdx.x * blockDim.x + threadIdx.x;
  if (t < 524288) { conv8(X + (size_t)t * 8, Xbf + (size_t)t * 8, 1.f); return; }
  t -= 524288;
  if (t < 131072) { conv8(Wq + (size_t)t * 8, Wcat + (size_t)t * 8, 0.125f); return; }   // fold D^-0.5
  t -= 131072;
  if (t < 131072) { conv8(Wk + (size_t)t * 8, Wcat + 1048576 + (size_t)t * 8, 1.f); return; }
  t -= 131072;
  if (t < 131072) { conv8(Wv + (size_t)t * 8, Wcat + 2097152 + (size_t)t * 8, 1.f); return; }
  t -= 131072;
  if (t < 131072) { conv8(Wo + (size_t)t * 8, Wobf + (size_t)t * 8, 1.f); return; }
  t -= 131072;
  if (t < 128) { copy8f(bq + t * 8, bcat + t * 8, 0.125f); return; }
  t -= 128;
  if (t < 128) { copy8f(bk + t * 8, bcat + 1024 + t * 8, 1.f); return; }
  t -= 128;
  if (t < 128) { copy8f(bv + t * 8, bcat + 2048 + t * 8, 1.f); return; }
}

// ---------------- bf16 GEMM, BK=32, XOR-swizzled LDS, depth-2 counted-vmcnt pipeline ----------
// Round-4 change (T3+T4-lite): 3 LDS buffers, raw s_barrier, counted s_waitcnt vmcnt(LPW).
// Schedule per iter i:  vmcnt(LPW) -> s_barrier -> stage(tile i+2) -> ds_read buf[i%3] -> MFMA.
//   RAW: tile i's loads are this wave's OLDEST LPW outstanding vm-ops (issued at iter i-2);
//        vmcnt(LPW) completes them; s_barrier extends the guarantee to all waves.
//        Tile i+1's LPW loads stay IN FLIGHT across the barrier (the T4 win; __syncthreads
//        would emit vmcnt(0) and drain them -> m233's 72% 2-phase stall).
//   WAR: stage at iter i overwrites buf[(i+2)%3] == buf[(i-1)%3], last read at iter i-1.
//        Every wave's iter i-1 ds_reads were consumed by its MFMAs (lgkm drained) before it
//        reached iter i's barrier, and stage is issued AFTER that barrier -> no race.
//   Last iteration uses vmcnt(0) (no newer loads exist to count past).
// Swizzle unchanged: slot q of row r stored at q^((r>>1)&3), applied on the GLOBAL source
// address (global_load_lds dest must be linear base + lane*16B); frag reads land 2-way.
template <int BN, bool OUT_BF16>
__global__ __launch_bounds__(256)
void gemm_bt(const u16* __restrict__ A, const u16* __restrict__ Bt,
             const float* __restrict__ bias, u16* __restrict__ Cbf,
             float* __restrict__ Cf, int M, int N, int K) {
  constexpr int SEG_A = 8;            // 128 rows / 16 rows-per-1KiB-segment
  constexpr int SEG_B = BN / 16;
  constexpr int NSEG = SEG_A + SEG_B; // 16 (BN=128) or 12 (BN=64); both /4
  constexpr int LPW = NSEG / 4;       // global_load_lds per wave per stage: 4 or 3
  constexpr int NI = BN / 32;         // per-wave N-tiles (wave covers 64 x BN/2)
  __shared__ u16 As[3][128 * 32];     // 3-deep: BN=128 -> 48 KiB total (3 blk/CU),
  __shared__ u16 Bs[3][BN * 32];      //         BN=64  -> 36 KiB total
  const int wv = threadIdx.x >> 6;
  const int lane = threadIdx.x & 63;
  const int bm = blockIdx.x, bn = blockIdx.y;
  const int wm = wv >> 1, wn = wv & 1;          // 2x2 wave grid
  const int lrow = lane & 15, quad = lane >> 4;

  f32x4 acc[4][NI];
#pragma unroll
  for (int i = 0; i < 4; ++i)
#pragma unroll
    for (int j = 0; j < NI; ++j) acc[i][j] = (f32x4){0.f, 0.f, 0.f, 0.f};

  const long arow = (long)bm * 128;
  const long brow = (long)bn * BN;
  // staging: segment s covers rows s*16..s*16+15; lane -> row srow = lane>>2,
  // LDS slot = lane&3; source col-block = (lane&3)^((lane>>3)&3)
  const int srow = lane >> 2;
  const int scol = ((lane & 3) ^ ((lane >> 3) & 3)) * 8;   // element offset in row
  const int swz = (quad ^ ((lrow >> 1) & 3)) * 8;          // frag-read slot offset (elements)

  auto stage = [&](int nb, int k0) {
#pragma unroll
    for (int it = 0; it < LPW; ++it) {
      const int s = wv * LPW + it;              // wave-uniform segment id
      const u16* g;
      u16* l;
      if (s < SEG_A) {
        g = A + (arow + s * 16 + srow) * K + k0 + scol;
        l = (u16*)As[nb] + s * 512;             // wave-uniform LDS base; HW adds lane*16B
      } else {
        g = Bt + (brow + (s - SEG_A) * 16 + srow) * K + k0 + scol;
        l = (u16*)Bs[nb] + (s - SEG_A) * 512;
      }
      __builtin_amdgcn_global_load_lds((AS1 void*)g, (AS3 void*)l, 16, 0, 0);
    }
  };

  const int T = K >> 5;                         // K/32 tiles (K=1024 -> 32)
  stage(0, 0);                                  // prologue: depth-2 prefetch
  stage(1, 32);
  int cb = 0;                                   // compute buffer index (i % 3)
  for (int i = 0; i < T; ++i) {
    if (i < T - 1) {
      // wait ONLY for tile i's loads (oldest LPW); tile i+1's stay in flight
      if constexpr (LPW == 4) asm volatile("s_waitcnt vmcnt(4)" ::: "memory");
      else                    asm volatile("s_waitcnt vmcnt(3)" ::: "memory");
    } else {
      asm volatile("s_waitcnt vmcnt(0)" ::: "memory");
    }
    __builtin_amdgcn_s_barrier();
    if (i + 2 < T) {
      const int sb = (cb + 2 >= 3) ? cb - 1 : cb + 2;
      stage(sb, (i + 2) * 32);
    }

    const u16* Ab = As[cb];
    const u16* Bb = Bs[cb];
    short8 af[4], bfr[NI];
#pragma unroll
    for (int mi = 0; mi < 4; ++mi)
      af[mi] = *(const short8*)(Ab + (wm * 64 + mi * 16 + lrow) * 32 + swz);
#pragma unroll
    for (int ni = 0; ni < NI; ++ni)
      bfr[ni] = *(const short8*)(Bb + (wn * (BN / 2) + ni * 16 + lrow) * 32 + swz);
#pragma unroll
    for (int mi = 0; mi < 4; ++mi)
#pragma unroll
      for (int ni = 0; ni < NI; ++ni)
        acc[mi][ni] = __builtin_amdgcn_mfma_f32_16x16x32_bf16(af[mi], bfr[ni], acc[mi][ni], 0, 0, 0);
    cb = (cb == 2) ? 0 : cb + 1;
  }

  // epilogue: C/D layout col=lane&15, row=quad*4+r (verified m89/m91)
#pragma unroll
  for (int mi = 0; mi < 4; ++mi) {
#pragma unroll
    for (int ni = 0; ni < NI; ++ni) {
      const int col = bn * BN + wn * (BN / 2) + ni * 16 + lrow;
      const float bv = bias[col];
#pragma unroll
      for (int r = 0; r < 4; ++r) {
        const int row = bm * 128 + wm * 64 + mi * 16 + quad * 4 + r;
        const float v = acc[mi][ni][r] + bv;
        if constexpr (OUT_BF16) Cbf[(long)row * N + col] = f2bf(v);
        else Cf[(long)row * N + col] = v;
      }
    }
  }
}

// ---------------- MFMA windowed attention: one wave per (b,h,chunk) ----------------
// allowed keys for query i: [max(0,i-25), chunk_end)  (contiguous, <=35)
#define NCH 205  // ceil(2048/10)
#define VT_STRIDE 68   // u16; 136B rows: 8B aligned (b64 reads), 2-way read conflict only
#define PB_STRIDE 72   // u16; 144B rows: 16B aligned (b128 reads)
#define WAVE_LDS (64 * VT_STRIDE + 16 * PB_STRIDE)   // 5504 u16 = 11008 B

__global__ __launch_bounds__(256)
void attn_kernel(const u16* __restrict__ QKV, u16* __restrict__ ctx) {
  __shared__ __align__(16) u16 lds[4 * WAVE_LDS];
  const int wv = threadIdx.x >> 6;
  const int lane = threadIdx.x & 63;
  u16* Vt = lds + wv * WAVE_LDS;      // [64 d][68] bf16 (V^T, zero-padded)
  u16* Pb = Vt + 64 * VT_STRIDE;      // [16 q][72] bf16 (P in row-major for A-frag)

  const int n = lane & 15, quad = lane >> 4;

  const int gw = blockIdx.x * 4 + wv;           // 6560 waves exactly
  const int b = gw / (16 * NCH);
  int rem = gw - b * 16 * NCH;
  const int h = rem / NCH;
  const int c = rem - h * NCH;
  const int cs = c * 10;
  const int nq = min(10, 2048 - cs);
  const int w0 = max(cs - 25, 0);
  const int L = cs + nq - w0;                   // window length <= 35

  const long base = ((long)b * 2048) * 3072 + (long)h * 64;

  // zero Vt and Pb (so MFMA pad regions multiply as 0, no NaN risk)
  for (int idx = lane; idx < (64 * VT_STRIDE) / 8; idx += 64)
    *(uint4*)(Vt + idx * 8) = (uint4){0, 0, 0, 0};
  for (int idx = lane; idx < (16 * PB_STRIDE) / 8; idx += 64)
    *(uint4*)(Pb + idx * 8) = (uint4){0, 0, 0, 0};

  // stage V transposed: Vt[d=lane][j] = V[w0+j][d]  (coalesced 128B global reads)
  for (int j = 0; j < L; ++j)
    Vt[lane * VT_STRIDE + j] = QKV[base + (long)(w0 + j) * 3072 + 2048 + lane];

  // ---- scores = Q * K^T via MFMA (M=16 pad, N=48 = 3 tiles, K=64) ----
  // A-frag: lane holds Q[m=n][k=quad*8+idx+32*s]  (direct 16B global loads)
  const int mclamp = min(n, nq - 1);
  const long qrow = base + (long)(cs + mclamp) * 3072;
  short8 aq0 = *(const short8*)(QKV + qrow + quad * 8);
  short8 aq1 = *(const short8*)(QKV + qrow + 32 + quad * 8);

  f32x4 sc[3];
#pragma unroll
  for (int t = 0; t < 3; ++t) {
    const int jj = min(16 * t + n, L - 1);      // clamp: garbage masked later
    const long krow = base + (long)(w0 + jj) * 3072 + 1024;
    short8 bk0 = *(const short8*)(QKV + krow + quad * 8);
    short8 bk1 = *(const short8*)(QKV + krow + 32 + quad * 8);
    f32x4 z = (f32x4){0.f, 0.f, 0.f, 0.f};
    z = __builtin_amdgcn_mfma_f32_16x16x32_bf16(aq0, bk0, z, 0, 0, 0);
    sc[t] = __builtin_amdgcn_mfma_f32_16x16x32_bf16(aq1, bk1, z, 0, 0, 0);
  }

  // ---- softmax in C-layout (col = 16t+n, row = quad*4+r), write P to LDS bf16 ----
#pragma unroll
  for (int r = 0; r < 4; ++r) {
    const int i = cs + quad * 4 + r;            // query index (rows >= nq are garbage, unstored)
    const int jlo = max(i - 25, 0) - w0;
    float v0 = (n >= jlo && n < L)      ? sc[0][r] : -1e30f;
    float v1 = (16 + n >= jlo && 16 + n < L) ? sc[1][r] : -1e30f;
    float v2 = (32 + n >= jlo && 32 + n < L) ? sc[2][r] : -1e30f;
    float m = fmaxf(v0, fmaxf(v1, v2));
#pragma unroll
    for (int off = 8; off > 0; off >>= 1) m = fmaxf(m, __shfl_xor(m, off));  // 16-lane row groups
    float p0 = __expf(v0 - m), p1 = __expf(v1 - m), p2 = __expf(v2 - m);
    float sum = p0 + p1 + p2;
#pragma unroll
    for (int off = 8; off > 0; off >>= 1) sum += __shfl_xor(sum, off);
    const float inv = 1.f / sum;
    u16* prow = Pb + (quad * 4 + r) * PB_STRIDE;
    prow[n]      = f2bf(p0 * inv);
    prow[16 + n] = f2bf(p1 * inv);
    prow[32 + n] = f2bf(p2 * inv);
  }
  // same-wave LDS RAW: DS pipe in-order per wave; compiler inserts lgkmcnt waits

  // ---- O = P * V via MFMA (M=16, N=64 = 4 tiles, K=64: j padded with zeros) ----
  short8 ap0 = *(const short8*)(Pb + n * PB_STRIDE + quad * 8);        // k = quad*8+idx
  short8 ap1 = *(const short8*)(Pb + n * PB_STRIDE + 32 + quad * 8);   // k = 32+quad*8+idx (zeros >= L)
  f32x4 o[4];
#pragma unroll
  for (int dt = 0; dt < 4; ++dt) {
    const u16* vrow = Vt + (dt * 16 + n) * VT_STRIDE;   // Bt[n=d][k=j] = V^T
    short4v l0 = *(const short4v*)(vrow + quad * 8);
    short4v h0 = *(const short4v*)(vrow + quad * 8 + 4);
    short4v l1 = *(const short4v*)(vrow + 32 + quad * 8);
    short4v h1 = *(const short4v*)(vrow + 32 + quad * 8 + 4);
    short8 bv0 = __builtin_shufflevector(l0, h0, 0, 1, 2, 3, 4, 5, 6, 7);
    short8 bv1 = __builtin_shufflevector(l1, h1, 0, 1, 2, 3, 4, 5, 6, 7);
    f32x4 z = (f32x4){0.f, 0.f, 0.f, 0.f};
    z = __builtin_amdgcn_mfma_f32_16x16x32_bf16(ap0, bv0, z, 0, 0, 0);
    o[dt] = __builtin_amdgcn_mfma_f32_16x16x32_bf16(ap1, bv1, z, 0, 0, 0);
  }

  // ---- store (C-layout: col = d within tile, row = quad*4+r) ----
#pragma unroll
  for (int dt = 0; dt < 4; ++dt) {
#pragma unroll
    for (int r = 0; r < 4; ++r) {
      const int row = quad * 4 + r;
      if (row < nq)
        ctx[((long)b * 2048 + cs + row) * 1024 + h * 64 + dt * 16 + n] = f2bf(o[dt][r]);
    }
  }
}

extern "C" void kernel_launch(void* const* d_in, const int* in_sizes, int n_in,
                              void* d_out, int out_size, void* d_ws, size_t ws_size,
                              hipStream_t stream) {
  const float* X  = (const float*)d_in[0];
  const float* Wq = (const float*)d_in[1];
  const float* bq = (const float*)d_in[2];
  const float* Wk = (const float*)d_in[3];
  const float* bk = (const float*)d_in[4];
  const float* Wv = (const float*)d_in[5];
  const float* bv = (const float*)d_in[6];
  const float* Wo = (const float*)d_in[7];
  const float* bo = (const float*)d_in[8];
  float* out = (float*)d_out;

  char* ws = (char*)d_ws;
  u16* Xbf   = (u16*)(ws);                  // [4096,1024] bf16   8,388,608 B
  u16* Wcat  = (u16*)(ws + 8388608);        // [3072,1024] bf16   6,291,456 B
  u16* Wobf  = (u16*)(ws + 14680064);       // [1024,1024] bf16   2,097,152 B
  float* bcat = (float*)(ws + 16777216);    // [3072] f32            12,288 B
  u16* QKV   = (u16*)(ws + 16789504);       // [4096,3072] bf16  25,165,824 B
  u16* ctx   = (u16*)(ws + 41955328);       // [4096,1024] bf16   8,388,608 B

  pack_kernel<<<4098, 256, 0, stream>>>(X, Wq, bq, Wk, bk, Wv, bv, Wo, Xbf, Wcat, Wobf, bcat);
  gemm_bt<128, true ><<<dim3(32, 24), 256, 0, stream>>>(Xbf, Wcat, bcat, QKV, nullptr, 4096, 3072, 1024);
  attn_kernel<<<1640, 256, 0, stream>>>(QKV, ctx);
  gemm_bt<64, false><<<dim3(32, 16), 256, 0, stream>>>(ctx, Wobf, bo, nullptr, out, 4096, 1024, 1024);
}

// Round 5
// 165.876 us; speedup vs baseline: 1.0015x; 1.0015x over previous
//
#include <hip/hip_runtime.h>
#include <stdint.h>

typedef unsigned short u16;
typedef __attribute__((ext_vector_type(8))) short short8;   // 8 x bf16 (4 VGPRs)
typedef __attribute__((ext_vector_type(4))) short short4v;  // 4 x bf16
typedef __attribute__((ext_vector_type(4))) float f32x4;

#define AS1 __attribute__((address_space(1)))
#define AS3 __attribute__((address_space(3)))

__device__ __forceinline__ u16 f2bf(float f) {
  uint32_t x = __builtin_bit_cast(uint32_t, f);
  uint32_t r = (x + 0x7fffu + ((x >> 16) & 1u)) >> 16;   // RNE
  return (u16)r;
}
__device__ __forceinline__ float bf2f(u16 u) {
  return __builtin_bit_cast(float, (uint32_t)u << 16);
}

// ---------------- pack: fp32 -> bf16 conversions + weight concat ----------------
__device__ __forceinline__ void conv8(const float* __restrict__ s, u16* __restrict__ d, float sc) {
  float4 a = *(const float4*)s;
  float4 b = *(const float4*)(s + 4);
  union { u16 u[8]; uint4 v; } pk;
  pk.u[0] = f2bf(a.x * sc); pk.u[1] = f2bf(a.y * sc); pk.u[2] = f2bf(a.z * sc); pk.u[3] = f2bf(a.w * sc);
  pk.u[4] = f2bf(b.x * sc); pk.u[5] = f2bf(b.y * sc); pk.u[6] = f2bf(b.z * sc); pk.u[7] = f2bf(b.w * sc);
  *(uint4*)d = pk.v;
}
__device__ __forceinline__ void copy8f(const float* __restrict__ s, float* __restrict__ d, float sc) {
  float4 a = *(const float4*)s;
  float4 b = *(const float4*)(s + 4);
  a.x *= sc; a.y *= sc; a.z *= sc; a.w *= sc;
  b.x *= sc; b.y *= sc; b.z *= sc; b.w *= sc;
  *(float4*)d = a; *(float4*)(d + 4) = b;
}

__global__ void pack_kernel(const float* __restrict__ X,
                            const float* __restrict__ Wq, const float* __restrict__ bq,
                            const float* __restrict__ Wk, const float* __restrict__ bk,
                            const float* __restrict__ Wv, const float* __restrict__ bv,
                            const float* __restrict__ Wo,
                            u16* __restrict__ Xbf, u16* __restrict__ Wcat,
                            u16* __restrict__ Wobf, float* __restrict__ bcat) {
  int t = blockIdx.x * blockDim.x + threadIdx.x;
  if (t < 524288) { conv8(X + (size_t)t * 8, Xbf + (size_t)t * 8, 1.f); return; }
  t -= 524288;
  if (t < 131072) { conv8(Wq + (size_t)t * 8, Wcat + (size_t)t * 8, 0.125f); return; }   // fold D^-0.5
  t -= 131072;
  if (t < 131072) { conv8(Wk + (size_t)t * 8, Wcat + 1048576 + (size_t)t * 8, 1.f); return; }
  t -= 131072;
  if (t < 131072) { conv8(Wv + (size_t)t * 8, Wcat + 2097152 + (size_t)t * 8, 1.f); return; }
  t -= 131072;
  if (t < 131072) { conv8(Wo + (size_t)t * 8, Wobf + (size_t)t * 8, 1.f); return; }
  t -= 131072;
  if (t < 128) { copy8f(bq + t * 8, bcat + t * 8, 0.125f); return; }
  t -= 128;
  if (t < 128) { copy8f(bk + t * 8, bcat + 1024 + t * 8, 1.f); return; }
  t -= 128;
  if (t < 128) { copy8f(bv + t * 8, bcat + 2048 + t * 8, 1.f); return; }
}

// ---------------- bf16 GEMM, BK=32, XOR-swizzled LDS, 2-phase prefetch + XCD swizzle ----------
// 2-buffer __syncthreads structure (best measured baseline) + bijective XCD-aware block
// swizzle (m157/m204). HW dispatches linear blockIdx round-robin across the 8 XCDs;
// remap new = (old&7)*cpx + (old>>3) so each XCD gets a CONTIGUOUS id chunk. With bm-fast
// decode, the ~32 blocks concurrently resident on one XCD share ONE B-panel (0.79 MB,
// L2-resident) instead of every XCD pulling every panel through L3/HBM -> lower average
// load latency (we are latency-bound: 15% HBM BW, MfmaUtil 22%) and less HBM over-fetch
// (FETCH 28.7 MB vs 14.7 MB unique). Requires gridDim.x % 8 == 0: 768 and 512 qualify.
template <int BN, bool OUT_BF16>
__global__ __launch_bounds__(256)
void gemm_bt(const u16* __restrict__ A, const u16* __restrict__ Bt,
             const float* __restrict__ bias, u16* __restrict__ Cbf,
             float* __restrict__ Cf, int M, int N, int K) {
  constexpr int SEG_A = 8;            // 128 rows / 16 rows-per-1KiB-segment
  constexpr int SEG_B = BN / 16;
  constexpr int NSEG = SEG_A + SEG_B; // 16 (BN=128) or 12 (BN=64); both /4
  constexpr int NI = BN / 32;         // per-wave N-tiles (wave covers 64 x BN/2)
  __shared__ u16 As[2][128 * 32];
  __shared__ u16 Bs[2][BN * 32];
  const int wv = threadIdx.x >> 6;
  const int lane = threadIdx.x & 63;

  // XCD-aware bijective remap, then bm-fast decode (M = 4096 -> 32 bm tiles always)
  const int cpx = gridDim.x >> 3;
  const int lin = (blockIdx.x & 7) * cpx + (blockIdx.x >> 3);
  const int bm = lin & 31;
  const int bn = lin >> 5;

  const int wm = wv >> 1, wn = wv & 1;          // 2x2 wave grid
  const int lrow = lane & 15, quad = lane >> 4;

  f32x4 acc[4][NI];
#pragma unroll
  for (int i = 0; i < 4; ++i)
#pragma unroll
    for (int j = 0; j < NI; ++j) acc[i][j] = (f32x4){0.f, 0.f, 0.f, 0.f};

  const long arow = (long)bm * 128;
  const long brow = (long)bn * BN;
  // staging: segment s covers rows s*16..s*16+15; lane -> row srow = lane>>2,
  // LDS slot = lane&3; source col-block = (lane&3)^((lane>>3)&3)
  const int srow = lane >> 2;
  const int scol = ((lane & 3) ^ ((lane >> 3) & 3)) * 8;   // element offset in row
  const int swz = (quad ^ ((lrow >> 1) & 3)) * 8;          // frag-read slot offset (elements)

  auto stage = [&](int nb, int k0) {
#pragma unroll
    for (int it = 0; it < NSEG / 4; ++it) {
      const int s = wv * (NSEG / 4) + it;       // wave-uniform segment id
      const u16* g;
      u16* l;
      if (s < SEG_A) {
        g = A + (arow + s * 16 + srow) * K + k0 + scol;
        l = (u16*)As[nb] + s * 512;             // wave-uniform LDS base; HW adds lane*16B
      } else {
        g = Bt + (brow + (s - SEG_A) * 16 + srow) * K + k0 + scol;
        l = (u16*)Bs[nb] + (s - SEG_A) * 512;
      }
      __builtin_amdgcn_global_load_lds((AS1 void*)g, (AS3 void*)l, 16, 0, 0);
    }
  };

  stage(0, 0);                                  // prologue: tile 0 into buffer 0
  int cur = 0;
  for (int k0 = 0; k0 < K; k0 += 32) {
    // barrier drains this wave's outstanding global_load_lds (vmcnt) -> buf[cur] ready,
    // and guarantees every wave finished its ds_reads of buf[cur^1] last iteration.
    __syncthreads();
    if (k0 + 32 < K) stage(cur ^ 1, k0 + 32);   // prefetch next tile; drains NEXT iter

    short8 af[4], bfr[NI];
#pragma unroll
    for (int mi = 0; mi < 4; ++mi)
      af[mi] = *(const short8*)(As[cur] + (wm * 64 + mi * 16 + lrow) * 32 + swz);
#pragma unroll
    for (int ni = 0; ni < NI; ++ni)
      bfr[ni] = *(const short8*)(Bs[cur] + (wn * (BN / 2) + ni * 16 + lrow) * 32 + swz);
#pragma unroll
    for (int mi = 0; mi < 4; ++mi)
#pragma unroll
      for (int ni = 0; ni < NI; ++ni)
        acc[mi][ni] = __builtin_amdgcn_mfma_f32_16x16x32_bf16(af[mi], bfr[ni], acc[mi][ni], 0, 0, 0);
    cur ^= 1;
  }

  // epilogue: C/D layout col=lane&15, row=quad*4+r (verified m89/m91)
#pragma unroll
  for (int mi = 0; mi < 4; ++mi) {
#pragma unroll
    for (int ni = 0; ni < NI; ++ni) {
      const int col = bn * BN + wn * (BN / 2) + ni * 16 + lrow;
      const float bv = bias[col];
#pragma unroll
      for (int r = 0; r < 4; ++r) {
        const int row = bm * 128 + wm * 64 + mi * 16 + quad * 4 + r;
        const float v = acc[mi][ni][r] + bv;
        if constexpr (OUT_BF16) Cbf[(long)row * N + col] = f2bf(v);
        else Cf[(long)row * N + col] = v;
      }
    }
  }
}

// ---------------- MFMA windowed attention: one wave per (b,h,chunk) ----------------
// allowed keys for query i: [max(0,i-25), chunk_end)  (contiguous, <=35)
// XCD swizzle: adjacent chunks share 25/35 K/V rows; contiguous chunk ids per XCD keep
// that overlap in the XCD's private L2. 1640 % 8 == 0 -> bijective.
#define NCH 205  // ceil(2048/10)
#define VT_STRIDE 68   // u16; 136B rows: 8B aligned (b64 reads), 2-way read conflict only
#define PB_STRIDE 72   // u16; 144B rows: 16B aligned (b128 reads)
#define WAVE_LDS (64 * VT_STRIDE + 16 * PB_STRIDE)   // 5504 u16 = 11008 B

__global__ __launch_bounds__(256)
void attn_kernel(const u16* __restrict__ QKV, u16* __restrict__ ctx) {
  __shared__ __align__(16) u16 lds[4 * WAVE_LDS];
  const int wv = threadIdx.x >> 6;
  const int lane = threadIdx.x & 63;
  u16* Vt = lds + wv * WAVE_LDS;      // [64 d][68] bf16 (V^T, zero-padded)
  u16* Pb = Vt + 64 * VT_STRIDE;      // [16 q][72] bf16 (P in row-major for A-frag)

  const int n = lane & 15, quad = lane >> 4;

  const int blk = (blockIdx.x & 7) * 205 + (blockIdx.x >> 3);   // XCD-contiguous remap
  const int gw = blk * 4 + wv;                  // 6560 waves exactly
  const int b = gw / (16 * NCH);
  int rem = gw - b * 16 * NCH;
  const int h = rem / NCH;
  const int c = rem - h * NCH;
  const int cs = c * 10;
  const int nq = min(10, 2048 - cs);
  const int w0 = max(cs - 25, 0);
  const int L = cs + nq - w0;                   // window length <= 35

  const long base = ((long)b * 2048) * 3072 + (long)h * 64;

  // zero Vt and Pb (so MFMA pad regions multiply as 0, no NaN risk)
  for (int idx = lane; idx < (64 * VT_STRIDE) / 8; idx += 64)
    *(uint4*)(Vt + idx * 8) = (uint4){0, 0, 0, 0};
  for (int idx = lane; idx < (16 * PB_STRIDE) / 8; idx += 64)
    *(uint4*)(Pb + idx * 8) = (uint4){0, 0, 0, 0};

  // stage V transposed: Vt[d=lane][j] = V[w0+j][d]  (coalesced 128B global reads)
  for (int j = 0; j < L; ++j)
    Vt[lane * VT_STRIDE + j] = QKV[base + (long)(w0 + j) * 3072 + 2048 + lane];

  // ---- scores = Q * K^T via MFMA (M=16 pad, N=48 = 3 tiles, K=64) ----
  // A-frag: lane holds Q[m=n][k=quad*8+idx+32*s]  (direct 16B global loads)
  const int mclamp = min(n, nq - 1);
  const long qrow = base + (long)(cs + mclamp) * 3072;
  short8 aq0 = *(const short8*)(QKV + qrow + quad * 8);
  short8 aq1 = *(const short8*)(QKV + qrow + 32 + quad * 8);

  f32x4 sc[3];
#pragma unroll
  for (int t = 0; t < 3; ++t) {
    const int jj = min(16 * t + n, L - 1);      // clamp: garbage masked later
    const long krow = base + (long)(w0 + jj) * 3072 + 1024;
    short8 bk0 = *(const short8*)(QKV + krow + quad * 8);
    short8 bk1 = *(const short8*)(QKV + krow + 32 + quad * 8);
    f32x4 z = (f32x4){0.f, 0.f, 0.f, 0.f};
    z = __builtin_amdgcn_mfma_f32_16x16x32_bf16(aq0, bk0, z, 0, 0, 0);
    sc[t] = __builtin_amdgcn_mfma_f32_16x16x32_bf16(aq1, bk1, z, 0, 0, 0);
  }

  // ---- softmax in C-layout (col = 16t+n, row = quad*4+r), write P to LDS bf16 ----
#pragma unroll
  for (int r = 0; r < 4; ++r) {
    const int i = cs + quad * 4 + r;            // query index (rows >= nq are garbage, unstored)
    const int jlo = max(i - 25, 0) - w0;
    float v0 = (n >= jlo && n < L)      ? sc[0][r] : -1e30f;
    float v1 = (16 + n >= jlo && 16 + n < L) ? sc[1][r] : -1e30f;
    float v2 = (32 + n >= jlo && 32 + n < L) ? sc[2][r] : -1e30f;
    float m = fmaxf(v0, fmaxf(v1, v2));
#pragma unroll
    for (int off = 8; off > 0; off >>= 1) m = fmaxf(m, __shfl_xor(m, off));  // 16-lane row groups
    float p0 = __expf(v0 - m), p1 = __expf(v1 - m), p2 = __expf(v2 - m);
    float sum = p0 + p1 + p2;
#pragma unroll
    for (int off = 8; off > 0; off >>= 1) sum += __shfl_xor(sum, off);
    const float inv = 1.f / sum;
    u16* prow = Pb + (quad * 4 + r) * PB_STRIDE;
    prow[n]      = f2bf(p0 * inv);
    prow[16 + n] = f2bf(p1 * inv);
    prow[32 + n] = f2bf(p2 * inv);
  }
  // same-wave LDS RAW: DS pipe in-order per wave; compiler inserts lgkmcnt waits

  // ---- O = P * V via MFMA (M=16, N=64 = 4 tiles, K=64: j padded with zeros) ----
  short8 ap0 = *(const short8*)(Pb + n * PB_STRIDE + quad * 8);        // k = quad*8+idx
  short8 ap1 = *(const short8*)(Pb + n * PB_STRIDE + 32 + quad * 8);   // k = 32+quad*8+idx (zeros >= L)
  f32x4 o[4];
#pragma unroll
  for (int dt = 0; dt < 4; ++dt) {
    const u16* vrow = Vt + (dt * 16 + n) * VT_STRIDE;   // Bt[n=d][k=j] = V^T
    short4v l0 = *(const short4v*)(vrow + quad * 8);
    short4v h0 = *(const short4v*)(vrow + quad * 8 + 4);
    short4v l1 = *(const short4v*)(vrow + 32 + quad * 8);
    short4v h1 = *(const short4v*)(vrow + 32 + quad * 8 + 4);
    short8 bv0 = __builtin_shufflevector(l0, h0, 0, 1, 2, 3, 4, 5, 6, 7);
    short8 bv1 = __builtin_shufflevector(l1, h1, 0, 1, 2, 3, 4, 5, 6, 7);
    f32x4 z = (f32x4){0.f, 0.f, 0.f, 0.f};
    z = __builtin_amdgcn_mfma_f32_16x16x32_bf16(ap0, bv0, z, 0, 0, 0);
    o[dt] = __builtin_amdgcn_mfma_f32_16x16x32_bf16(ap1, bv1, z, 0, 0, 0);
  }

  // ---- store (C-layout: col = d within tile, row = quad*4+r) ----
#pragma unroll
  for (int dt = 0; dt < 4; ++dt) {
#pragma unroll
    for (int r = 0; r < 4; ++r) {
      const int row = quad * 4 + r;
      if (row < nq)
        ctx[((long)b * 2048 + cs + row) * 1024 + h * 64 + dt * 16 + n] = f2bf(o[dt][r]);
    }
  }
}

extern "C" void kernel_launch(void* const* d_in, const int* in_sizes, int n_in,
                              void* d_out, int out_size, void* d_ws, size_t ws_size,
                              hipStream_t stream) {
  const float* X  = (const float*)d_in[0];
  const float* Wq = (const float*)d_in[1];
  const float* bq = (const float*)d_in[2];
  const float* Wk = (const float*)d_in[3];
  const float* bk = (const float*)d_in[4];
  const float* Wv = (const float*)d_in[5];
  const float* bv = (const float*)d_in[6];
  const float* Wo = (const float*)d_in[7];
  const float* bo = (const float*)d_in[8];
  float* out = (float*)d_out;

  char* ws = (char*)d_ws;
  u16* Xbf   = (u16*)(ws);                  // [4096,1024] bf16   8,388,608 B
  u16* Wcat  = (u16*)(ws + 8388608);        // [3072,1024] bf16   6,291,456 B
  u16* Wobf  = (u16*)(ws + 14680064);       // [1024,1024] bf16   2,097,152 B
  float* bcat = (float*)(ws + 16777216);    // [3072] f32            12,288 B
  u16* QKV   = (u16*)(ws + 16789504);       // [4096,3072] bf16  25,165,824 B
  u16* ctx   = (u16*)(ws + 41955328);       // [4096,1024] bf16   8,388,608 B

  pack_kernel<<<4098, 256, 0, stream>>>(X, Wq, bq, Wk, bk, Wv, bv, Wo, Xbf, Wcat, Wobf, bcat);
  gemm_bt<128, true ><<<768, 256, 0, stream>>>(Xbf, Wcat, bcat, QKV, nullptr, 4096, 3072, 1024);
  attn_kernel<<<1640, 256, 0, stream>>>(QKV, ctx);
  gemm_bt<64, false><<<512, 256, 0, stream>>>(ctx, Wobf, bo, nullptr, out, 4096, 1024, 1024);
}

// Round 6
// 162.504 us; speedup vs baseline: 1.0223x; 1.0207x over previous
//
#include <hip/hip_runtime.h>
#include <stdint.h>

typedef unsigned short u16;
typedef __attribute__((ext_vector_type(8))) short short8;   // 8 x bf16 (4 VGPRs)
typedef __attribute__((ext_vector_type(4))) short short4v;  // 4 x bf16
typedef __attribute__((ext_vector_type(4))) float f32x4;

#define AS1 __attribute__((address_space(1)))
#define AS3 __attribute__((address_space(3)))

__device__ __forceinline__ u16 f2bf(float f) {
  uint32_t x = __builtin_bit_cast(uint32_t, f);
  uint32_t r = (x + 0x7fffu + ((x >> 16) & 1u)) >> 16;   // RNE
  return (u16)r;
}
__device__ __forceinline__ float bf2f(u16 u) {
  return __builtin_bit_cast(float, (uint32_t)u << 16);
}

// ---------------- pack: fp32 -> bf16 conversions + weight concat ----------------
__device__ __forceinline__ void conv8(const float* __restrict__ s, u16* __restrict__ d, float sc) {
  float4 a = *(const float4*)s;
  float4 b = *(const float4*)(s + 4);
  union { u16 u[8]; uint4 v; } pk;
  pk.u[0] = f2bf(a.x * sc); pk.u[1] = f2bf(a.y * sc); pk.u[2] = f2bf(a.z * sc); pk.u[3] = f2bf(a.w * sc);
  pk.u[4] = f2bf(b.x * sc); pk.u[5] = f2bf(b.y * sc); pk.u[6] = f2bf(b.z * sc); pk.u[7] = f2bf(b.w * sc);
  *(uint4*)d = pk.v;
}
__device__ __forceinline__ void copy8f(const float* __restrict__ s, float* __restrict__ d, float sc) {
  float4 a = *(const float4*)s;
  float4 b = *(const float4*)(s + 4);
  a.x *= sc; a.y *= sc; a.z *= sc; a.w *= sc;
  b.x *= sc; b.y *= sc; b.z *= sc; b.w *= sc;
  *(float4*)d = a; *(float4*)(d + 4) = b;
}

__global__ void pack_kernel(const float* __restrict__ X,
                            const float* __restrict__ Wq, const float* __restrict__ bq,
                            const float* __restrict__ Wk, const float* __restrict__ bk,
                            const float* __restrict__ Wv, const float* __restrict__ bv,
                            const float* __restrict__ Wo,
                            u16* __restrict__ Xbf, u16* __restrict__ Wcat,
                            u16* __restrict__ Wobf, float* __restrict__ bcat) {
  int t = blockIdx.x * blockDim.x + threadIdx.x;
  if (t < 524288) { conv8(X + (size_t)t * 8, Xbf + (size_t)t * 8, 1.f); return; }
  t -= 524288;
  if (t < 131072) { conv8(Wq + (size_t)t * 8, Wcat + (size_t)t * 8, 0.125f); return; }   // fold D^-0.5
  t -= 131072;
  if (t < 131072) { conv8(Wk + (size_t)t * 8, Wcat + 1048576 + (size_t)t * 8, 1.f); return; }
  t -= 131072;
  if (t < 131072) { conv8(Wv + (size_t)t * 8, Wcat + 2097152 + (size_t)t * 8, 1.f); return; }
  t -= 131072;
  if (t < 131072) { conv8(Wo + (size_t)t * 8, Wobf + (size_t)t * 8, 1.f); return; }
  t -= 131072;
  if (t < 128) { copy8f(bq + t * 8, bcat + t * 8, 0.125f); return; }
  t -= 128;
  if (t < 128) { copy8f(bk + t * 8, bcat + 1024 + t * 8, 1.f); return; }
  t -= 128;
  if (t < 128) { copy8f(bv + t * 8, bcat + 2048 + t * 8, 1.f); return; }
}

// ---------------- bf16 GEMM, BK=32, XOR-swizzled LDS, 2-phase prefetch, 8 waves ----------
// Round-6: XCD swizzle REVERTED (neutral-to-negative: operands fit aggregate L2, swizzle
// only perturbed dispatch). Single new variable: 512-thread blocks (8 waves) at CONSTANT
// tile/grid/LDS. Each wave owns 64x32 (BN=128) or 32x32 (BN=64); MFMA issue per CU per
// K-step unchanged, but waves/CU doubles (12 -> 24 for gemm1) so stage latency + barrier
// drain hide behind 2x the independent streams. Accumulator VGPR halves per wave.
// 2-buffer __syncthreads ledger unchanged (verified round 2):
//   barrier drains vmcnt -> buf[cur] ready; stage(cur^1) issued after barrier, drains at
//   the NEXT barrier, so global->LDS latency hides under a full compute phase.
// Swizzle unchanged: slot q of row r stored at q^((r>>1)&3), applied on the GLOBAL source
// address (global_load_lds dest must be linear base + lane*16B); frag reads land 2-way.
template <int BN, bool OUT_BF16>
__global__ __launch_bounds__(512)
void gemm_bt(const u16* __restrict__ A, const u16* __restrict__ Bt,
             const float* __restrict__ bias, u16* __restrict__ Cbf,
             float* __restrict__ Cf, int M, int N, int K) {
  constexpr int SEG_A = 8;            // 128 rows / 16 rows-per-1KiB-segment
  constexpr int SEG_B = BN / 16;
  constexpr int NSEG = SEG_A + SEG_B; // 16 (BN=128) or 12 (BN=64)
  constexpr int NWN = BN / 32;        // waves along N (each covers 32 cols): 4 or 2
  constexpr int NWM = 8 / NWN;        // waves along M: 2 or 4
  constexpr int MI = 128 / (NWM * 16);// M-frags per wave: 4 or 2
  __shared__ u16 As[2][128 * 32];
  __shared__ u16 Bs[2][BN * 32];
  const int wv = threadIdx.x >> 6;    // 0..7
  const int lane = threadIdx.x & 63;
  const int bm = blockIdx.x, bn = blockIdx.y;
  const int wm = wv / NWN, wn = wv % NWN;
  const int lrow = lane & 15, quad = lane >> 4;

  f32x4 acc[MI][2];
#pragma unroll
  for (int i = 0; i < MI; ++i)
#pragma unroll
    for (int j = 0; j < 2; ++j) acc[i][j] = (f32x4){0.f, 0.f, 0.f, 0.f};

  const long arow = (long)bm * 128;
  const long brow = (long)bn * BN;
  // staging: segment s covers rows s*16..s*16+15; lane -> row srow = lane>>2,
  // LDS slot = lane&3; source col-block = (lane&3)^((lane>>3)&3)
  const int srow = lane >> 2;
  const int scol = ((lane & 3) ^ ((lane >> 3) & 3)) * 8;   // element offset in row
  const int swz = (quad ^ ((lrow >> 1) & 3)) * 8;          // frag-read slot offset (elements)

  auto stage = [&](int nb, int k0) {
#pragma unroll
    for (int it = 0; it < 2; ++it) {
      const int s = wv + it * 8;                // wave-uniform segment id
      if (s < NSEG) {                           // wave-uniform guard (NSEG=12 case)
        const u16* g;
        u16* l;
        if (s < SEG_A) {
          g = A + (arow + s * 16 + srow) * K + k0 + scol;
          l = (u16*)As[nb] + s * 512;           // wave-uniform LDS base; HW adds lane*16B
        } else {
          g = Bt + (brow + (s - SEG_A) * 16 + srow) * K + k0 + scol;
          l = (u16*)Bs[nb] + (s - SEG_A) * 512;
        }
        __builtin_amdgcn_global_load_lds((AS1 void*)g, (AS3 void*)l, 16, 0, 0);
      }
    }
  };

  stage(0, 0);                                  // prologue: tile 0 into buffer 0
  int cur = 0;
  for (int k0 = 0; k0 < K; k0 += 32) {
    // barrier drains this wave's outstanding global_load_lds (vmcnt) -> buf[cur] ready,
    // and guarantees every wave finished its ds_reads of buf[cur^1] last iteration.
    __syncthreads();
    if (k0 + 32 < K) stage(cur ^ 1, k0 + 32);   // prefetch next tile; drains NEXT iter

    short8 af[MI], bfr[2];
#pragma unroll
    for (int mi = 0; mi < MI; ++mi)
      af[mi] = *(const short8*)(As[cur] + (wm * (MI * 16) + mi * 16 + lrow) * 32 + swz);
#pragma unroll
    for (int ni = 0; ni < 2; ++ni)
      bfr[ni] = *(const short8*)(Bs[cur] + (wn * 32 + ni * 16 + lrow) * 32 + swz);
#pragma unroll
    for (int mi = 0; mi < MI; ++mi)
#pragma unroll
      for (int ni = 0; ni < 2; ++ni)
        acc[mi][ni] = __builtin_amdgcn_mfma_f32_16x16x32_bf16(af[mi], bfr[ni], acc[mi][ni], 0, 0, 0);
    cur ^= 1;
  }

  // epilogue: C/D layout col=lane&15, row=quad*4+r (verified m89/m91)
#pragma unroll
  for (int mi = 0; mi < MI; ++mi) {
#pragma unroll
    for (int ni = 0; ni < 2; ++ni) {
      const int col = bn * BN + wn * 32 + ni * 16 + lrow;
      const float bv = bias[col];
#pragma unroll
      for (int r = 0; r < 4; ++r) {
        const int row = bm * 128 + wm * (MI * 16) + mi * 16 + quad * 4 + r;
        const float v = acc[mi][ni][r] + bv;
        if constexpr (OUT_BF16) Cbf[(long)row * N + col] = f2bf(v);
        else Cf[(long)row * N + col] = v;
      }
    }
  }
}

// ---------------- MFMA windowed attention: one wave per (b,h,chunk) ----------------
// allowed keys for query i: [max(0,i-25), chunk_end)  (contiguous, <=35)
#define NCH 205  // ceil(2048/10)
#define VT_STRIDE 68   // u16; 136B rows: 8B aligned (b64 reads), 2-way read conflict only
#define PB_STRIDE 72   // u16; 144B rows: 16B aligned (b128 reads)
#define WAVE_LDS (64 * VT_STRIDE + 16 * PB_STRIDE)   // 5504 u16 = 11008 B

__global__ __launch_bounds__(256)
void attn_kernel(const u16* __restrict__ QKV, u16* __restrict__ ctx) {
  __shared__ __align__(16) u16 lds[4 * WAVE_LDS];
  const int wv = threadIdx.x >> 6;
  const int lane = threadIdx.x & 63;
  u16* Vt = lds + wv * WAVE_LDS;      // [64 d][68] bf16 (V^T, zero-padded)
  u16* Pb = Vt + 64 * VT_STRIDE;      // [16 q][72] bf16 (P in row-major for A-frag)

  const int n = lane & 15, quad = lane >> 4;

  const int gw = blockIdx.x * 4 + wv;           // 6560 waves exactly
  const int b = gw / (16 * NCH);
  int rem = gw - b * 16 * NCH;
  const int h = rem / NCH;
  const int c = rem - h * NCH;
  const int cs = c * 10;
  const int nq = min(10, 2048 - cs);
  const int w0 = max(cs - 25, 0);
  const int L = cs + nq - w0;                   // window length <= 35

  const long base = ((long)b * 2048) * 3072 + (long)h * 64;

  // zero Vt and Pb (so MFMA pad regions multiply as 0, no NaN risk)
  for (int idx = lane; idx < (64 * VT_STRIDE) / 8; idx += 64)
    *(uint4*)(Vt + idx * 8) = (uint4){0, 0, 0, 0};
  for (int idx = lane; idx < (16 * PB_STRIDE) / 8; idx += 64)
    *(uint4*)(Pb + idx * 8) = (uint4){0, 0, 0, 0};

  // stage V transposed: Vt[d=lane][j] = V[w0+j][d]  (coalesced 128B global reads)
  for (int j = 0; j < L; ++j)
    Vt[lane * VT_STRIDE + j] = QKV[base + (long)(w0 + j) * 3072 + 2048 + lane];

  // ---- scores = Q * K^T via MFMA (M=16 pad, N=48 = 3 tiles, K=64) ----
  // A-frag: lane holds Q[m=n][k=quad*8+idx+32*s]  (direct 16B global loads)
  const int mclamp = min(n, nq - 1);
  const long qrow = base + (long)(cs + mclamp) * 3072;
  short8 aq0 = *(const short8*)(QKV + qrow + quad * 8);
  short8 aq1 = *(const short8*)(QKV + qrow + 32 + quad * 8);

  f32x4 sc[3];
#pragma unroll
  for (int t = 0; t < 3; ++t) {
    const int jj = min(16 * t + n, L - 1);      // clamp: garbage masked later
    const long krow = base + (long)(w0 + jj) * 3072 + 1024;
    short8 bk0 = *(const short8*)(QKV + krow + quad * 8);
    short8 bk1 = *(const short8*)(QKV + krow + 32 + quad * 8);
    f32x4 z = (f32x4){0.f, 0.f, 0.f, 0.f};
    z = __builtin_amdgcn_mfma_f32_16x16x32_bf16(aq0, bk0, z, 0, 0, 0);
    sc[t] = __builtin_amdgcn_mfma_f32_16x16x32_bf16(aq1, bk1, z, 0, 0, 0);
  }

  // ---- softmax in C-layout (col = 16t+n, row = quad*4+r), write P to LDS bf16 ----
#pragma unroll
  for (int r = 0; r < 4; ++r) {
    const int i = cs + quad * 4 + r;            // query index (rows >= nq are garbage, unstored)
    const int jlo = max(i - 25, 0) - w0;
    float v0 = (n >= jlo && n < L)      ? sc[0][r] : -1e30f;
    float v1 = (16 + n >= jlo && 16 + n < L) ? sc[1][r] : -1e30f;
    float v2 = (32 + n >= jlo && 32 + n < L) ? sc[2][r] : -1e30f;
    float m = fmaxf(v0, fmaxf(v1, v2));
#pragma unroll
    for (int off = 8; off > 0; off >>= 1) m = fmaxf(m, __shfl_xor(m, off));  // 16-lane row groups
    float p0 = __expf(v0 - m), p1 = __expf(v1 - m), p2 = __expf(v2 - m);
    float sum = p0 + p1 + p2;
#pragma unroll
    for (int off = 8; off > 0; off >>= 1) sum += __shfl_xor(sum, off);
    const float inv = 1.f / sum;
    u16* prow = Pb + (quad * 4 + r) * PB_STRIDE;
    prow[n]      = f2bf(p0 * inv);
    prow[16 + n] = f2bf(p1 * inv);
    prow[32 + n] = f2bf(p2 * inv);
  }
  // same-wave LDS RAW: DS pipe in-order per wave; compiler inserts lgkmcnt waits

  // ---- O = P * V via MFMA (M=16, N=64 = 4 tiles, K=64: j padded with zeros) ----
  short8 ap0 = *(const short8*)(Pb + n * PB_STRIDE + quad * 8);        // k = quad*8+idx
  short8 ap1 = *(const short8*)(Pb + n * PB_STRIDE + 32 + quad * 8);   // k = 32+quad*8+idx (zeros >= L)
  f32x4 o[4];
#pragma unroll
  for (int dt = 0; dt < 4; ++dt) {
    const u16* vrow = Vt + (dt * 16 + n) * VT_STRIDE;   // Bt[n=d][k=j] = V^T
    short4v l0 = *(const short4v*)(vrow + quad * 8);
    short4v h0 = *(const short4v*)(vrow + quad * 8 + 4);
    short4v l1 = *(const short4v*)(vrow + 32 + quad * 8);
    short4v h1 = *(const short4v*)(vrow + 32 + quad * 8 + 4);
    short8 bv0 = __builtin_shufflevector(l0, h0, 0, 1, 2, 3, 4, 5, 6, 7);
    short8 bv1 = __builtin_shufflevector(l1, h1, 0, 1, 2, 3, 4, 5, 6, 7);
    f32x4 z = (f32x4){0.f, 0.f, 0.f, 0.f};
    z = __builtin_amdgcn_mfma_f32_16x16x32_bf16(ap0, bv0, z, 0, 0, 0);
    o[dt] = __builtin_amdgcn_mfma_f32_16x16x32_bf16(ap1, bv1, z, 0, 0, 0);
  }

  // ---- store (C-layout: col = d within tile, row = quad*4+r) ----
#pragma unroll
  for (int dt = 0; dt < 4; ++dt) {
#pragma unroll
    for (int r = 0; r < 4; ++r) {
      const int row = quad * 4 + r;
      if (row < nq)
        ctx[((long)b * 2048 + cs + row) * 1024 + h * 64 + dt * 16 + n] = f2bf(o[dt][r]);
    }
  }
}

extern "C" void kernel_launch(void* const* d_in, const int* in_sizes, int n_in,
                              void* d_out, int out_size, void* d_ws, size_t ws_size,
                              hipStream_t stream) {
  const float* X  = (const float*)d_in[0];
  const float* Wq = (const float*)d_in[1];
  const float* bq = (const float*)d_in[2];
  const float* Wk = (const float*)d_in[3];
  const float* bk = (const float*)d_in[4];
  const float* Wv = (const float*)d_in[5];
  const float* bv = (const float*)d_in[6];
  const float* Wo = (const float*)d_in[7];
  const float* bo = (const float*)d_in[8];
  float* out = (float*)d_out;

  char* ws = (char*)d_ws;
  u16* Xbf   = (u16*)(ws);                  // [4096,1024] bf16   8,388,608 B
  u16* Wcat  = (u16*)(ws + 8388608);        // [3072,1024] bf16   6,291,456 B
  u16* Wobf  = (u16*)(ws + 14680064);       // [1024,1024] bf16   2,097,152 B
  float* bcat = (float*)(ws + 16777216);    // [3072] f32            12,288 B
  u16* QKV   = (u16*)(ws + 16789504);       // [4096,3072] bf16  25,165,824 B
  u16* ctx   = (u16*)(ws + 41955328);       // [4096,1024] bf16   8,388,608 B

  pack_kernel<<<4098, 256, 0, stream>>>(X, Wq, bq, Wk, bk, Wv, bv, Wo, Xbf, Wcat, Wobf, bcat);
  gemm_bt<128, true ><<<dim3(32, 24), 512, 0, stream>>>(Xbf, Wcat, bcat, QKV, nullptr, 4096, 3072, 1024);
  attn_kernel<<<1640, 256, 0, stream>>>(QKV, ctx);
  gemm_bt<64, false><<<dim3(32, 16), 512, 0, stream>>>(ctx, Wobf, bo, nullptr, out, 4096, 1024, 1024);
}

// Round 7
// 157.339 us; speedup vs baseline: 1.0558x; 1.0328x over previous
//
#include <hip/hip_runtime.h>
#include <stdint.h>

typedef unsigned short u16;
typedef __attribute__((ext_vector_type(8))) short short8;   // 8 x bf16 (4 VGPRs)
typedef __attribute__((ext_vector_type(4))) short short4v;  // 4 x bf16
typedef __attribute__((ext_vector_type(4))) float f32x4;

#define AS1 __attribute__((address_space(1)))
#define AS3 __attribute__((address_space(3)))

__device__ __forceinline__ u16 f2bf(float f) {
  uint32_t x = __builtin_bit_cast(uint32_t, f);
  uint32_t r = (x + 0x7fffu + ((x >> 16) & 1u)) >> 16;   // RNE
  return (u16)r;
}
__device__ __forceinline__ float bf2f(u16 u) {
  return __builtin_bit_cast(float, (uint32_t)u << 16);
}

// ---------------- pack: fp32 -> bf16 conversions + weight concat ----------------
__device__ __forceinline__ void conv8(const float* __restrict__ s, u16* __restrict__ d, float sc) {
  float4 a = *(const float4*)s;
  float4 b = *(const float4*)(s + 4);
  union { u16 u[8]; uint4 v; } pk;
  pk.u[0] = f2bf(a.x * sc); pk.u[1] = f2bf(a.y * sc); pk.u[2] = f2bf(a.z * sc); pk.u[3] = f2bf(a.w * sc);
  pk.u[4] = f2bf(b.x * sc); pk.u[5] = f2bf(b.y * sc); pk.u[6] = f2bf(b.z * sc); pk.u[7] = f2bf(b.w * sc);
  *(uint4*)d = pk.v;
}
__device__ __forceinline__ void copy8f(const float* __restrict__ s, float* __restrict__ d, float sc) {
  float4 a = *(const float4*)s;
  float4 b = *(const float4*)(s + 4);
  a.x *= sc; a.y *= sc; a.z *= sc; a.w *= sc;
  b.x *= sc; b.y *= sc; b.z *= sc; b.w *= sc;
  *(float4*)d = a; *(float4*)(d + 4) = b;
}

__global__ void pack_kernel(const float* __restrict__ X,
                            const float* __restrict__ Wq, const float* __restrict__ bq,
                            const float* __restrict__ Wk, const float* __restrict__ bk,
                            const float* __restrict__ Wv, const float* __restrict__ bv,
                            const float* __restrict__ Wo,
                            u16* __restrict__ Xbf, u16* __restrict__ Wcat,
                            u16* __restrict__ Wobf, float* __restrict__ bcat) {
  int t = blockIdx.x * blockDim.x + threadIdx.x;
  if (t < 524288) { conv8(X + (size_t)t * 8, Xbf + (size_t)t * 8, 1.f); return; }
  t -= 524288;
  if (t < 131072) { conv8(Wq + (size_t)t * 8, Wcat + (size_t)t * 8, 0.125f); return; }   // fold D^-0.5
  t -= 131072;
  if (t < 131072) { conv8(Wk + (size_t)t * 8, Wcat + 1048576 + (size_t)t * 8, 1.f); return; }
  t -= 131072;
  if (t < 131072) { conv8(Wv + (size_t)t * 8, Wcat + 2097152 + (size_t)t * 8, 1.f); return; }
  t -= 131072;
  if (t < 131072) { conv8(Wo + (size_t)t * 8, Wobf + (size_t)t * 8, 1.f); return; }
  t -= 131072;
  if (t < 128) { copy8f(bq + t * 8, bcat + t * 8, 0.125f); return; }
  t -= 128;
  if (t < 128) { copy8f(bk + t * 8, bcat + 1024 + t * 8, 1.f); return; }
  t -= 128;
  if (t < 128) { copy8f(bv + t * 8, bcat + 2048 + t * 8, 1.f); return; }
}

// ---------------- bf16 GEMM, BK=32, XOR-swizzled LDS, 2-phase prefetch, 8 waves ----------
// (unchanged from round 6 — best measured GEMM config)
template <int BN, bool OUT_BF16>
__global__ __launch_bounds__(512)
void gemm_bt(const u16* __restrict__ A, const u16* __restrict__ Bt,
             const float* __restrict__ bias, u16* __restrict__ Cbf,
             float* __restrict__ Cf, int M, int N, int K) {
  constexpr int SEG_A = 8;            // 128 rows / 16 rows-per-1KiB-segment
  constexpr int SEG_B = BN / 16;
  constexpr int NSEG = SEG_A + SEG_B; // 16 (BN=128) or 12 (BN=64)
  constexpr int NWN = BN / 32;        // waves along N (each covers 32 cols): 4 or 2
  constexpr int NWM = 8 / NWN;        // waves along M: 2 or 4
  constexpr int MI = 128 / (NWM * 16);// M-frags per wave: 4 or 2
  __shared__ u16 As[2][128 * 32];
  __shared__ u16 Bs[2][BN * 32];
  const int wv = threadIdx.x >> 6;    // 0..7
  const int lane = threadIdx.x & 63;
  const int bm = blockIdx.x, bn = blockIdx.y;
  const int wm = wv / NWN, wn = wv % NWN;
  const int lrow = lane & 15, quad = lane >> 4;

  f32x4 acc[MI][2];
#pragma unroll
  for (int i = 0; i < MI; ++i)
#pragma unroll
    for (int j = 0; j < 2; ++j) acc[i][j] = (f32x4){0.f, 0.f, 0.f, 0.f};

  const long arow = (long)bm * 128;
  const long brow = (long)bn * BN;
  // staging: segment s covers rows s*16..s*16+15; lane -> row srow = lane>>2,
  // LDS slot = lane&3; source col-block = (lane&3)^((lane>>3)&3)
  const int srow = lane >> 2;
  const int scol = ((lane & 3) ^ ((lane >> 3) & 3)) * 8;   // element offset in row
  const int swz = (quad ^ ((lrow >> 1) & 3)) * 8;          // frag-read slot offset (elements)

  auto stage = [&](int nb, int k0) {
#pragma unroll
    for (int it = 0; it < 2; ++it) {
      const int s = wv + it * 8;                // wave-uniform segment id
      if (s < NSEG) {                           // wave-uniform guard (NSEG=12 case)
        const u16* g;
        u16* l;
        if (s < SEG_A) {
          g = A + (arow + s * 16 + srow) * K + k0 + scol;
          l = (u16*)As[nb] + s * 512;           // wave-uniform LDS base; HW adds lane*16B
        } else {
          g = Bt + (brow + (s - SEG_A) * 16 + srow) * K + k0 + scol;
          l = (u16*)Bs[nb] + (s - SEG_A) * 512;
        }
        __builtin_amdgcn_global_load_lds((AS1 void*)g, (AS3 void*)l, 16, 0, 0);
      }
    }
  };

  stage(0, 0);                                  // prologue: tile 0 into buffer 0
  int cur = 0;
  for (int k0 = 0; k0 < K; k0 += 32) {
    // barrier drains this wave's outstanding global_load_lds (vmcnt) -> buf[cur] ready,
    // and guarantees every wave finished its ds_reads of buf[cur^1] last iteration.
    __syncthreads();
    if (k0 + 32 < K) stage(cur ^ 1, k0 + 32);   // prefetch next tile; drains NEXT iter

    short8 af[MI], bfr[2];
#pragma unroll
    for (int mi = 0; mi < MI; ++mi)
      af[mi] = *(const short8*)(As[cur] + (wm * (MI * 16) + mi * 16 + lrow) * 32 + swz);
#pragma unroll
    for (int ni = 0; ni < 2; ++ni)
      bfr[ni] = *(const short8*)(Bs[cur] + (wn * 32 + ni * 16 + lrow) * 32 + swz);
#pragma unroll
    for (int mi = 0; mi < MI; ++mi)
#pragma unroll
      for (int ni = 0; ni < 2; ++ni)
        acc[mi][ni] = __builtin_amdgcn_mfma_f32_16x16x32_bf16(af[mi], bfr[ni], acc[mi][ni], 0, 0, 0);
    cur ^= 1;
  }

  // epilogue: C/D layout col=lane&15, row=quad*4+r (verified m89/m91)
#pragma unroll
  for (int mi = 0; mi < MI; ++mi) {
#pragma unroll
    for (int ni = 0; ni < 2; ++ni) {
      const int col = bn * BN + wn * 32 + ni * 16 + lrow;
      const float bv = bias[col];
#pragma unroll
      for (int r = 0; r < 4; ++r) {
        const int row = bm * 128 + wm * (MI * 16) + mi * 16 + quad * 4 + r;
        const float v = acc[mi][ni][r] + bv;
        if constexpr (OUT_BF16) Cbf[(long)row * N + col] = f2bf(v);
        else Cf[(long)row * N + col] = v;
      }
    }
  }
}

// ---------------- MFMA windowed attention: one wave per (b,h,chunk) ----------------
// Round-7 rewrite of V path:
//  - V staged ROW-MAJOR Vr[j][64] via 16B vector loads (5 iters/lane) + 2x ds_write_b64
//    (replaces 35 serial scalar global loads + scalar LDS writes of the V^T layout).
//  - No V zero-fill: PV reads clamp the row index to min(j, L-1). Any k >= L has
//    P == exactly 0 (expf underflow -> f2bf(0), and Pb cols 48.. are zero-init), so a
//    clamped FINITE real V row contributes exactly 0 -> value-identical output.
//  - PV B-frag: per-column ds_read_u16. VR_STRIDE=68 u16 (136B rows): quad step
//    8*68*2B = 1088B -> bank offset 16 words -> 2-way conflict only (free, m136).
//    Clamp hoisted: idx = min(ib + e*68, icap) (min commutes with monotone *68).
//  - LDS 11008 -> 7200 B/wave: 28.8 KB/block -> 5 blocks/CU (was 3), 20 waves/CU.
#define NCH 205  // ceil(2048/10)
#define VR_STRIDE 68   // u16; 136B rows: 8B-aligned b64 writes, 2-way PV read conflicts
#define PB_STRIDE 72   // u16; 144B rows: 16B aligned (b128 reads)
#define WAVE_LDS (36 * VR_STRIDE + 16 * PB_STRIDE)   // 2448 + 1152 = 3600 u16 = 7200 B

__global__ __launch_bounds__(256)
void attn_kernel(const u16* __restrict__ QKV, u16* __restrict__ ctx) {
  __shared__ __align__(16) u16 lds[4 * WAVE_LDS];
  const int wv = threadIdx.x >> 6;
  const int lane = threadIdx.x & 63;
  u16* Vr = lds + wv * WAVE_LDS;      // [36 j][68] bf16 row-major V (rows >= L unstaged)
  u16* Pb = Vr + 36 * VR_STRIDE;      // [16 q][72] bf16 (P in row-major for A-frag)

  const int n = lane & 15, quad = lane >> 4;

  const int gw = blockIdx.x * 4 + wv;           // 6560 waves exactly
  const int b = gw / (16 * NCH);
  int rem = gw - b * 16 * NCH;
  const int h = rem / NCH;
  const int c = rem - h * NCH;
  const int cs = c * 10;
  const int nq = min(10, 2048 - cs);
  const int w0 = max(cs - 25, 0);
  const int L = cs + nq - w0;                   // window length, 10 <= L <= 35

  const long base = ((long)b * 2048) * 3072 + (long)h * 64;

  // zero Pb only (cols 48..71 must stay exact 0 for the k>=48 MFMA half)
  for (int idx = lane; idx < (16 * PB_STRIDE) / 8; idx += 64)
    *(uint4*)(Pb + idx * 8) = (uint4){0, 0, 0, 0};

  // stage V row-major: Vr[j][d] = V[w0+j][d]; 16B loads, 2x 8B LDS writes
  // slot = it*64+lane covers (j = slot>>3, c8 = slot&7); 35 rows x 8 slots = 280 <= 320
#pragma unroll
  for (int it = 0; it < 5; ++it) {
    const int slot = it * 64 + lane;
    const int j = slot >> 3, c8 = slot & 7;
    if (j < L) {
      const uint4 v = *(const uint4*)(QKV + base + (long)(w0 + j) * 3072 + 2048 + c8 * 8);
      u16* wp = Vr + j * VR_STRIDE + c8 * 8;
      *(uint2*)wp = (uint2){v.x, v.y};
      *(uint2*)(wp + 4) = (uint2){v.z, v.w};
    }
  }

  // ---- scores = Q * K^T via MFMA (M=16 pad, N=48 = 3 tiles, K=64) ----
  // A-frag: lane holds Q[m=n][k=quad*8+idx+32*s]  (direct 16B global loads)
  const int mclamp = min(n, nq - 1);
  const long qrow = base + (long)(cs + mclamp) * 3072;
  short8 aq0 = *(const short8*)(QKV + qrow + quad * 8);
  short8 aq1 = *(const short8*)(QKV + qrow + 32 + quad * 8);

  f32x4 sc[3];
#pragma unroll
  for (int t = 0; t < 3; ++t) {
    const int jj = min(16 * t + n, L - 1);      // clamp: garbage masked later
    const long krow = base + (long)(w0 + jj) * 3072 + 1024;
    short8 bk0 = *(const short8*)(QKV + krow + quad * 8);
    short8 bk1 = *(const short8*)(QKV + krow + 32 + quad * 8);
    f32x4 z = (f32x4){0.f, 0.f, 0.f, 0.f};
    z = __builtin_amdgcn_mfma_f32_16x16x32_bf16(aq0, bk0, z, 0, 0, 0);
    sc[t] = __builtin_amdgcn_mfma_f32_16x16x32_bf16(aq1, bk1, z, 0, 0, 0);
  }

  // ---- softmax in C-layout (col = 16t+n, row = quad*4+r), write P to LDS bf16 ----
#pragma unroll
  for (int r = 0; r < 4; ++r) {
    const int i = cs + quad * 4 + r;            // query index (rows >= nq are garbage, unstored)
    const int jlo = max(i - 25, 0) - w0;
    float v0 = (n >= jlo && n < L)      ? sc[0][r] : -1e30f;
    float v1 = (16 + n >= jlo && 16 + n < L) ? sc[1][r] : -1e30f;
    float v2 = (32 + n >= jlo && 32 + n < L) ? sc[2][r] : -1e30f;
    float m = fmaxf(v0, fmaxf(v1, v2));
#pragma unroll
    for (int off = 8; off > 0; off >>= 1) m = fmaxf(m, __shfl_xor(m, off));  // 16-lane row groups
    float p0 = __expf(v0 - m), p1 = __expf(v1 - m), p2 = __expf(v2 - m);
    float sum = p0 + p1 + p2;
#pragma unroll
    for (int off = 8; off > 0; off >>= 1) sum += __shfl_xor(sum, off);
    const float inv = 1.f / sum;
    u16* prow = Pb + (quad * 4 + r) * PB_STRIDE;
    prow[n]      = f2bf(p0 * inv);
    prow[16 + n] = f2bf(p1 * inv);
    prow[32 + n] = f2bf(p2 * inv);
  }
  // same-wave LDS RAW: DS pipe in-order per wave; compiler inserts lgkmcnt waits

  // ---- O = P * V via MFMA (M=16, N=64 = 4 tiles, K=64) ----
  // B-frag columns from row-major Vr with clamped row index (P==0 for k>=L kills them)
  short8 ap0 = *(const short8*)(Pb + n * PB_STRIDE + quad * 8);        // k = quad*8+idx
  short8 ap1 = *(const short8*)(Pb + n * PB_STRIDE + 32 + quad * 8);   // k = 32+..  (P zero >= L)
  const int icap = (L - 1) * VR_STRIDE;         // clamp cap in u16 units
  const int ib0 = (quad * 8) * VR_STRIDE;       // bv0 row base
  const int ib1 = ib0 + 32 * VR_STRIDE;         // bv1 row base
  f32x4 o[4];
#pragma unroll
  for (int dt = 0; dt < 4; ++dt) {
    const u16* colp = Vr + dt * 16 + n;         // column base: d = dt*16+n
    short8 bv0, bv1;
#pragma unroll
    for (int e = 0; e < 8; ++e) {
      int i0 = ib0 + e * VR_STRIDE; i0 = i0 < icap ? i0 : icap;
      int i1 = ib1 + e * VR_STRIDE; i1 = i1 < icap ? i1 : icap;
      bv0[e] = (short)colp[i0];
      bv1[e] = (short)colp[i1];
    }
    f32x4 z = (f32x4){0.f, 0.f, 0.f, 0.f};
    z = __builtin_amdgcn_mfma_f32_16x16x32_bf16(ap0, bv0, z, 0, 0, 0);
    o[dt] = __builtin_amdgcn_mfma_f32_16x16x32_bf16(ap1, bv1, z, 0, 0, 0);
  }

  // ---- store (C-layout: col = d within tile, row = quad*4+r) ----
#pragma unroll
  for (int dt = 0; dt < 4; ++dt) {
#pragma unroll
    for (int r = 0; r < 4; ++r) {
      const int row = quad * 4 + r;
      if (row < nq)
        ctx[((long)b * 2048 + cs + row) * 1024 + h * 64 + dt * 16 + n] = f2bf(o[dt][r]);
    }
  }
}

extern "C" void kernel_launch(void* const* d_in, const int* in_sizes, int n_in,
                              void* d_out, int out_size, void* d_ws, size_t ws_size,
                              hipStream_t stream) {
  const float* X  = (const float*)d_in[0];
  const float* Wq = (const float*)d_in[1];
  const float* bq = (const float*)d_in[2];
  const float* Wk = (const float*)d_in[3];
  const float* bk = (const float*)d_in[4];
  const float* Wv = (const float*)d_in[5];
  const float* bv = (const float*)d_in[6];
  const float* Wo = (const float*)d_in[7];
  const float* bo = (const float*)d_in[8];
  float* out = (float*)d_out;

  char* ws = (char*)d_ws;
  u16* Xbf   = (u16*)(ws);                  // [4096,1024] bf16   8,388,608 B
  u16* Wcat  = (u16*)(ws + 8388608);        // [3072,1024] bf16   6,291,456 B
  u16* Wobf  = (u16*)(ws + 14680064);       // [1024,1024] bf16   2,097,152 B
  float* bcat = (float*)(ws + 16777216);    // [3072] f32            12,288 B
  u16* QKV   = (u16*)(ws + 16789504);       // [4096,3072] bf16  25,165,824 B
  u16* ctx   = (u16*)(ws + 41955328);       // [4096,1024] bf16   8,388,608 B

  pack_kernel<<<4098, 256, 0, stream>>>(X, Wq, bq, Wk, bk, Wv, bv, Wo, Xbf, Wcat, Wobf, bcat);
  gemm_bt<128, true ><<<dim3(32, 24), 512, 0, stream>>>(Xbf, Wcat, bcat, QKV, nullptr, 4096, 3072, 1024);
  attn_kernel<<<1640, 256, 0, stream>>>(QKV, ctx);
  gemm_bt<64, false><<<dim3(32, 16), 512, 0, stream>>>(ctx, Wobf, bo, nullptr, out, 4096, 1024, 1024);
}